// Round 1
// baseline (188.005 us; speedup 1.0000x reference)
//
#include <hip/hip_runtime.h>
#include <hip/hip_bf16.h>

#define NB  8
#define ENW 512
#define DEW 64
#define EMB 512
#define UN  512
#define NT  100

typedef short bf16x8 __attribute__((ext_vector_type(8)));
typedef float f32x4  __attribute__((ext_vector_type(4)));

__device__ __forceinline__ unsigned short f2bf(float f) {
    union { float f; unsigned int u; } v; v.f = f;
    unsigned int r = v.u + 0x7FFFu + ((v.u >> 16) & 1u);  // round-to-nearest-even
    return (unsigned short)(r >> 16);
}

__device__ __forceinline__ float fast_tanh(float x) {
    float e = __expf(2.0f * x);                       // v_exp_f32 path
    return 1.0f - 2.0f * __builtin_amdgcn_rcpf(e + 1.0f);
}

__device__ __forceinline__ float fast_sigmoid(float x) {
    return __builtin_amdgcn_rcpf(1.0f + __expf(-x));
}

// ---------------- conversion / prep kernels ----------------

__global__ __launch_bounds__(256) void cvt_f32_bf16(const float* __restrict__ in,
                                                    unsigned short* __restrict__ out, int n) {
    int idx = (blockIdx.x * 256 + threadIdx.x) * 4;
    if (idx < n) {
        float4 v = *(const float4*)(in + idx);
        ushort4 o;
        o.x = f2bf(v.x); o.y = f2bf(v.y); o.z = f2bf(v.z); o.w = f2bf(v.w);
        *(ushort4*)(out + idx) = o;
    }
}

// w: [E][U] fp32 -> wt: [U][E] bf16
__global__ __launch_bounds__(256) void transpose_to_bf16(const float* __restrict__ w,
                                                         unsigned short* __restrict__ wt) {
    int o = blockIdx.x * 256 + threadIdx.x;   // o = u*512 + e
    int u = o >> 9, e = o & 511;
    wt[o] = f2bf(w[e * 512 + u]);
}

// tw[b][u] = sum_t topics[b][t] * wt_mat[u][t]
__global__ __launch_bounds__(256) void topics_w_kernel(const float* __restrict__ topics,
                                                       const float* __restrict__ wt_mat,
                                                       float* __restrict__ tw) {
    int o = blockIdx.x * 256 + threadIdx.x;   // 0..4095 = b*512+u
    int b = o >> 9, u = o & 511;
    const float* tp = topics + b * NT;
    const float* wp = wt_mat + u * NT;
    float s = 0.f;
    for (int t = 0; t < NT; ++t) s += tp[t] * wp[t];
    tw[o] = s;
}

// ---------------- MFMA GEMM: C[M][512] = A[M][512] * Bt[512][512]^T ----------------
// A row-major [M][K] bf16, Bt row-major [N][K] bf16 (i.e. B transposed), C fp32 [M][N]
__global__ __launch_bounds__(256) void gemm_bf16(const unsigned short* __restrict__ A,
                                                 const unsigned short* __restrict__ Bt,
                                                 float* __restrict__ C, int M) {
    const int K = 512, N = 512;
    const int lane = threadIdx.x & 63;
    const int wave = threadIdx.x >> 6;
    const int m0 = blockIdx.x * 64 + wave * 16;
    const int n0 = blockIdx.y * 64;
    const int row = m0 + (lane & 15);
    const int kq  = (lane >> 4) * 8;          // k-offset of this lane's 8 contiguous elems

    f32x4 acc[4];
#pragma unroll
    for (int nn = 0; nn < 4; ++nn) acc[nn] = 0.f;

    const unsigned short* ap = A + (size_t)row * K + kq;
    for (int kc = 0; kc < K; kc += 32) {
        bf16x8 a = *(const bf16x8*)(ap + kc);
#pragma unroll
        for (int nn = 0; nn < 4; ++nn) {
            int n = n0 + nn * 16 + (lane & 15);
            bf16x8 b = *(const bf16x8*)(Bt + (size_t)n * K + kq + kc);
            acc[nn] = __builtin_amdgcn_mfma_f32_16x16x32_bf16(a, b, acc[nn], 0, 0, 0);
        }
    }
    // C/D layout: col = lane&15, row = (lane>>4)*4 + r   [guide §3, m89-verified]
    const int crow = m0 + (lane >> 4) * 4;
    const int ccol = lane & 15;
#pragma unroll
    for (int nn = 0; nn < 4; ++nn)
#pragma unroll
        for (int r = 0; r < 4; ++r)
            C[(size_t)(crow + r) * N + n0 + nn * 16 + ccol] = acc[nn][r];
}

// ---------------- mu[b][j][i] = sum_u nu[u]*tanh(att_en[b][i][u]+att_de[b][j][u]+tw[b][u]) --------
// grid: 1024 blocks = 8 i-splits x (8 b x 16 jgroups); 4 waves/block, wave = one j; lane owns u=8l..8l+7
__global__ __launch_bounds__(256) void mu_kernel(const float* __restrict__ att_en,
                                                 const float* __restrict__ att_de,
                                                 const float* __restrict__ tw,
                                                 const float* __restrict__ nu,
                                                 float* __restrict__ mu) {
    const int lane = threadIdx.x & 63;
    const int wave = threadIdx.x >> 6;
    const int grp    = blockIdx.x >> 3;   // 0..127
    const int isplit = blockIdx.x & 7;
    const int b  = grp >> 4;
    const int jg = grp & 15;
    const int j  = jg * 4 + wave;
    const int uo = lane * 8;

    const float* dp = att_de + (size_t)(b * DEW + j) * UN + uo;
    const float* tp = tw + b * UN + uo;
    const float* np = nu + uo;
    float bias[8], nuv[8];
#pragma unroll
    for (int q = 0; q < 8; ++q) { bias[q] = dp[q] + tp[q]; nuv[q] = np[q]; }

    const float* aep = att_en + (size_t)b * ENW * UN + uo;
    float* mup = mu + (size_t)(b * DEW + j) * ENW;
    const int i0 = isplit * 64;
    for (int i = i0; i < i0 + 64; ++i) {
        const float4* ap = (const float4*)(aep + (size_t)i * UN);
        float4 a0 = ap[0], a1 = ap[1];
        float s;
        s  = nuv[0] * fast_tanh(a0.x + bias[0]);
        s += nuv[1] * fast_tanh(a0.y + bias[1]);
        s += nuv[2] * fast_tanh(a0.z + bias[2]);
        s += nuv[3] * fast_tanh(a0.w + bias[3]);
        s += nuv[4] * fast_tanh(a1.x + bias[4]);
        s += nuv[5] * fast_tanh(a1.y + bias[5]);
        s += nuv[6] * fast_tanh(a1.z + bias[6]);
        s += nuv[7] * fast_tanh(a1.w + bias[7]);
#pragma unroll
        for (int off = 32; off > 0; off >>= 1) s += __shfl_down(s, off);
        if (lane == 0) mup[i] = s;
    }
}

// ---------------- softmax over i (EN) + p_gen ----------------
__global__ __launch_bounds__(256) void softmax_kernel(const float* __restrict__ mu,
                                                      float* __restrict__ alphas,
                                                      float* __restrict__ p_gen) {
    const int bj = blockIdx.x;            // 0..511
    const float* mup = mu + (size_t)bj * ENW;
    const int t = threadIdx.x;
    float v0 = mup[t], v1 = mup[t + 256];

    float m = fmaxf(v0, v1);
#pragma unroll
    for (int off = 32; off > 0; off >>= 1) m = fmaxf(m, __shfl_xor(m, off));
    __shared__ float wmax[4];
    if ((t & 63) == 0) wmax[t >> 6] = m;
    __syncthreads();
    m = fmaxf(fmaxf(wmax[0], wmax[1]), fmaxf(wmax[2], wmax[3]));

    float e0 = __expf(v0 - m), e1 = __expf(v1 - m);
    float s = e0 + e1;
#pragma unroll
    for (int off = 32; off > 0; off >>= 1) s += __shfl_xor(s, off);
    __shared__ float wsum[4];
    if ((t & 63) == 0) wsum[t >> 6] = s;
    __syncthreads();
    s = wsum[0] + wsum[1] + wsum[2] + wsum[3];
    float inv = __builtin_amdgcn_rcpf(s);

    alphas[(size_t)bj * ENW + t]       = e0 * inv;
    alphas[(size_t)bj * ENW + t + 256] = e1 * inv;
    p_gen[(size_t)bj * ENW + t]        = fast_sigmoid(v0);
    p_gen[(size_t)bj * ENW + t + 256]  = fast_sigmoid(v1);
}

// ---------------- out[b][j][e] = de[b][j][e] + sum_i alphas[b][j][i]*en[b][i][e] ----------------
// grid: (8, 4 e-tiles of 128, 4 j-groups of 16); 256 thr; thread tile 2j x 4e
__global__ __launch_bounds__(256) void out_kernel(const float* __restrict__ alphas,
                                                  const float* __restrict__ en,
                                                  const float* __restrict__ de,
                                                  float* __restrict__ out) {
    __shared__ float As[16][33];
    __shared__ float Es[32][128];
    const int b  = blockIdx.x;
    const int e0 = blockIdx.y * 128;
    const int j0 = blockIdx.z * 16;
    const int tid = threadIdx.x;
    const int tx = tid & 31, ty = tid >> 5;
    float acc[2][4] = {{0.f,0.f,0.f,0.f},{0.f,0.f,0.f,0.f}};
    const float* al = alphas + (size_t)(b * DEW + j0) * ENW;   // [16][512]
    const float* ep = en + (size_t)b * ENW * EMB;

    for (int ic = 0; ic < ENW; ic += 32) {
        {   // alphas chunk 16x32, 2 floats/thread
            int li = tid * 2;
            int jr = li >> 5, i = li & 31;
            float2 v = *(const float2*)(al + (size_t)jr * ENW + ic + i);
            As[jr][i] = v.x; As[jr][i + 1] = v.y;
        }
#pragma unroll
        for (int q = 0; q < 4; ++q) {   // en chunk 32x128, 16 floats/thread
            int li = (q * 256 + tid) * 4;
            int i = li >> 7, e = li & 127;
            float4 v = *(const float4*)(ep + (size_t)(ic + i) * EMB + e0 + e);
            *(float4*)&Es[i][e] = v;
        }
        __syncthreads();
#pragma unroll
        for (int i = 0; i < 32; ++i) {
            float a0 = As[ty * 2][i];
            float a1 = As[ty * 2 + 1][i];
            float4 ev = *(const float4*)&Es[i][tx * 4];
            acc[0][0] += a0 * ev.x; acc[0][1] += a0 * ev.y;
            acc[0][2] += a0 * ev.z; acc[0][3] += a0 * ev.w;
            acc[1][0] += a1 * ev.x; acc[1][1] += a1 * ev.y;
            acc[1][2] += a1 * ev.z; acc[1][3] += a1 * ev.w;
        }
        __syncthreads();
    }
#pragma unroll
    for (int jj = 0; jj < 2; ++jj) {
        int j = j0 + ty * 2 + jj;
        int e = e0 + tx * 4;
        float4 d = *(const float4*)(de + (size_t)(b * DEW + j) * EMB + e);
        float4 o;
        o.x = acc[jj][0] + d.x; o.y = acc[jj][1] + d.y;
        o.z = acc[jj][2] + d.z; o.w = acc[jj][3] + d.w;
        *(float4*)(out + (size_t)(b * DEW + j) * EMB + e) = o;
    }
}

extern "C" void kernel_launch(void* const* d_in, const int* in_sizes, int n_in,
                              void* d_out, int out_size, void* d_ws, size_t ws_size,
                              hipStream_t stream) {
    const float* en     = (const float*)d_in[0];  // [8][512][512]
    const float* de     = (const float*)d_in[1];  // [8][64][512]
    const float* topics = (const float*)d_in[2];  // [8][100]
    const float* w_en   = (const float*)d_in[3];  // [512][512]
    const float* w_de   = (const float*)d_in[4];  // [512][512]
    const float* nu     = (const float*)d_in[5];  // [512]
    const float* wt     = (const float*)d_in[6];  // [512][100]

    float* out    = (float*)d_out;        // [8][64][512]
    float* alphas = out + 262144;         // [8][64][512]
    float* p_gen  = out + 524288;         // [8][64][512]

    char* ws = (char*)d_ws;
    float* att_en         = (float*)(ws);                       // 8388608 B
    float* att_de         = (float*)(ws + 8388608);             // 1048576 B
    float* tw             = (float*)(ws + 9437184);             //   16384 B
    float* mu             = (float*)(ws + 9453568);             // 1048576 B
    unsigned short* en_bf = (unsigned short*)(ws + 10502144);   // 4194304 B
    unsigned short* de_bf = (unsigned short*)(ws + 14696448);   //  524288 B
    unsigned short* wen_t = (unsigned short*)(ws + 15220736);   //  524288 B
    unsigned short* wde_t = (unsigned short*)(ws + 15745024);   //  524288 B (end ~15.5 MiB)

    cvt_f32_bf16     <<<2048, 256, 0, stream>>>(en, en_bf, 2097152);
    cvt_f32_bf16     <<<256,  256, 0, stream>>>(de, de_bf, 262144);
    transpose_to_bf16<<<1024, 256, 0, stream>>>(w_en, wen_t);
    transpose_to_bf16<<<1024, 256, 0, stream>>>(w_de, wde_t);
    topics_w_kernel  <<<16,   256, 0, stream>>>(topics, wt, tw);

    gemm_bf16<<<dim3(64, 8), 256, 0, stream>>>(en_bf, wen_t, att_en, 4096);
    gemm_bf16<<<dim3(8, 8),  256, 0, stream>>>(de_bf, wde_t, att_de, 512);

    mu_kernel     <<<1024, 256, 0, stream>>>(att_en, att_de, tw, nu, mu);
    softmax_kernel<<<512,  256, 0, stream>>>(mu, alphas, p_gen);
    out_kernel    <<<dim3(8, 4, 4), 256, 0, stream>>>(alphas, en, de, out);
}